// Round 1
// 768.993 us; speedup vs baseline: 1.0632x; 1.0632x over previous
//
#include <hip/hip_runtime.h>
#include <hip/hip_bf16.h>

typedef __bf16 bf16_t;
typedef __bf16 bf16x8 __attribute__((ext_vector_type(8)));
typedef __bf16 bf16x4 __attribute__((ext_vector_type(4)));
typedef float  floatx4 __attribute__((ext_vector_type(4)));

#define DIM    1024
#define S_LEN  2048
#define NHEAD  16

// ---------------------------------------------------------------------------
// load 8 consecutive elements as bf16x8 (f32 source converts, bf16 is a copy)
// ---------------------------------------------------------------------------
template <typename T>
__device__ __forceinline__ bf16x8 load8bf(const T* src) {
  if constexpr (sizeof(T) == 2) {
    return *reinterpret_cast<const bf16x8*>(src);
  } else {
    floatx4 f0 = *reinterpret_cast<const floatx4*>(src);
    floatx4 f1 = *reinterpret_cast<const floatx4*>(src + 4);
    bf16x8 h;
    h[0] = (bf16_t)f0[0]; h[1] = (bf16_t)f0[1];
    h[2] = (bf16_t)f0[2]; h[3] = (bf16_t)f0[3];
    h[4] = (bf16_t)f1[0]; h[5] = (bf16_t)f1[1];
    h[6] = (bf16_t)f1[2]; h[7] = (bf16_t)f1[3];
    return h;
  }
}

// ---------------------------------------------------------------------------
// Weight transpose+convert, f32 KxN -> bf16 NxK. z selects among up to 3
// (in, ldi, out) triples (pass repeats for unused slots; grid.z trims).
// ---------------------------------------------------------------------------
__global__ __launch_bounds__(256) void convT3(
    const float* __restrict__ in0, int ldi0, bf16_t* __restrict__ out0,
    const float* __restrict__ in1, int ldi1, bf16_t* __restrict__ out1,
    const float* __restrict__ in2, int ldi2, bf16_t* __restrict__ out2,
    int ldo) {
  __shared__ bf16_t tile[32][33];
  const int z = blockIdx.z;
  const float* in = (z == 0) ? in0 : ((z == 1) ? in1 : in2);
  bf16_t* out = (z == 0) ? out0 : ((z == 1) ? out1 : out2);
  int ldi = (z == 0) ? ldi0 : ((z == 1) ? ldi1 : ldi2);
  int tx = threadIdx.x, ty = threadIdx.y;
  int n0 = blockIdx.x * 32, k0 = blockIdx.y * 32;
#pragma unroll
  for (int i = 0; i < 4; ++i)
    tile[ty + 8 * i][tx] = (bf16_t)in[(size_t)(k0 + ty + 8 * i) * ldi + n0 + tx];
  __syncthreads();
#pragma unroll
  for (int i = 0; i < 4; ++i)
    out[(size_t)(n0 + ty + 8 * i) * ldo + k0 + tx] = tile[tx][ty + 8 * i];
}

// ---------------------------------------------------------------------------
// GEMM: C(MxN) = A(MxK) @ Bt(NxK)^T + bias; optional ReLU / bf16-accumulate.
// A f32 or bf16 (converted during staging); Bt pre-transposed bf16 (ldbt=K).
// blockIdx.z: Bt row offset z*zBRow, C col offset z*zCOff, bias selection.
// 128x128 tile, BK=32, 4 waves, 4x4 MFMA. Verified gfx950 layouts.
// ---------------------------------------------------------------------------
#define BM 128
#define BN 128
#define BK 32
#define LSTR 40  // 32+8 pad: 80B row stride (16B multiple), 2-way bank = free

template <typename TA>
__global__ __launch_bounds__(256) void gemm_abt(
    const TA* __restrict__ A, int lda,
    const bf16_t* __restrict__ Bt, int zBRow,
    bf16_t* __restrict__ C, int ldc, int zCOff,
    const float* __restrict__ bias0, const float* __restrict__ bias1,
    const float* __restrict__ bias2,
    int K, int relu, int accum) {
  __shared__ bf16_t As[BM * LSTR];
  __shared__ bf16_t Bs[BN * LSTR];
  const int z = blockIdx.z;
  const float* bias = (z == 0) ? bias0 : ((z == 1) ? bias1 : bias2);
  const bf16_t* Bz = Bt + (size_t)z * zBRow * K;
  C += (size_t)z * zCOff;

  const int tid  = threadIdx.x;
  const int lane = tid & 63;
  const int wave = tid >> 6;
  const int wr   = wave >> 1;
  const int wc   = wave & 1;
  const int quad = lane >> 4;
  const int l15  = lane & 15;
  const int m0   = blockIdx.y * BM;
  const int n0   = blockIdx.x * BN;

  floatx4 acc[4][4];
#pragma unroll
  for (int i = 0; i < 4; ++i)
#pragma unroll
    for (int j = 0; j < 4; ++j) acc[i][j] = (floatx4)(0.0f);

  const int kIters = K / BK;
  for (int kt = 0; kt < kIters; ++kt) {
#pragma unroll
    for (int p = 0; p < 2; ++p) {
      int id  = p * 256 + tid;
      int row = id >> 2;
      int c8  = (id & 3) * 8;
      *reinterpret_cast<bf16x8*>(&As[row * LSTR + c8]) =
          load8bf(A + (size_t)(m0 + row) * lda + kt * BK + c8);
      *reinterpret_cast<bf16x8*>(&Bs[row * LSTR + c8]) =
          *reinterpret_cast<const bf16x8*>(Bz + (size_t)(n0 + row) * K + kt * BK + c8);
    }
    __syncthreads();

    bf16x8 a[4], b[4];
#pragma unroll
    for (int i = 0; i < 4; ++i)
      a[i] = *reinterpret_cast<const bf16x8*>(&As[(wr * 64 + i * 16 + l15) * LSTR + quad * 8]);
#pragma unroll
    for (int j = 0; j < 4; ++j)
      b[j] = *reinterpret_cast<const bf16x8*>(&Bs[(wc * 64 + j * 16 + l15) * LSTR + quad * 8]);
#pragma unroll
    for (int i = 0; i < 4; ++i)
#pragma unroll
      for (int j = 0; j < 4; ++j)
        acc[i][j] = __builtin_amdgcn_mfma_f32_16x16x32_bf16(a[i], b[j], acc[i][j], 0, 0, 0);
    __syncthreads();
  }

#pragma unroll
  for (int j = 0; j < 4; ++j) {
    int gn = n0 + wc * 64 + j * 16 + l15;
    float bv = bias ? bias[gn] : 0.0f;
#pragma unroll
    for (int i = 0; i < 4; ++i) {
      int gm = m0 + wr * 64 + i * 16 + quad * 4;
#pragma unroll
      for (int r = 0; r < 4; ++r) {
        float v = acc[i][j][r] + bv;
        if (relu) v = fmaxf(v, 0.0f);
        size_t idx = (size_t)(gm + r) * ldc + gn;
        if (accum) v += (float)C[idx];
        C[idx] = (bf16_t)v;
      }
    }
  }
}

// ---------------------------------------------------------------------------
// V transpose: per (pair-local batch z, head h), V slice [2048 s][64 d] from
// qkv2 (col offset 2048+h*64, row stride 3072) -> vt[bh][64 d][2048 s].
// ---------------------------------------------------------------------------
__global__ __launch_bounds__(256) void transpose_v(const bf16_t* __restrict__ in,
                                                   bf16_t* __restrict__ outp) {
  __shared__ bf16_t tile[32][33];
  int tx = threadIdx.x, ty = threadIdx.y;
  int s0 = blockIdx.x * 32, d0 = blockIdx.y * 32, bh = blockIdx.z;
  int z = bh >> 4, h = bh & 15;
  const bf16_t* src = in + (size_t)z * S_LEN * 3072 + 2048 + h * 64;
#pragma unroll
  for (int i = 0; i < 4; ++i)
    tile[ty + 8 * i][tx] = src[(size_t)(s0 + ty + 8 * i) * 3072 + d0 + tx];
  __syncthreads();
  bf16_t* dst = outp + (size_t)bh * 64 * S_LEN;
#pragma unroll
  for (int i = 0; i < 4; ++i)
    dst[(size_t)(d0 + ty + 8 * i) * S_LEN + s0 + tx] = tile[tx][ty + 8 * i];
}

// ---------------------------------------------------------------------------
// Paired MFMA flash attention, causal, scale 1/dph folded into Q staging.
// TQ=64 q-tiles, paired {pi, 31-pi} per block x (z,h): active tile-iters =
// (pi+1)+(32-pi) = 33, constant across blocks (balanced compute). Grid
// 16x16x2 = 512 blocks = 2 blocks/CU = 2 waves/SIMD (was 1 — the kernel was
// latency-bound at Occupancy 10%, MfmaUtil 6.4%). LDS 27.6KB/block so two
// blocks co-resident; launch_bounds(256,2) declares 2 waves/EU.
// K/V staged per k-tile (2x8KB); QsPs buffer: Q staging for tile A then B,
// then reused as P scratch (wave-private 16-row ranges; per-wave LDS ops
// are in-order -> no extra barriers).
// ---------------------------------------------------------------------------
#define TQ  64
#define TK  64
#define AST 72  // LDS row stride bf16: 144B (16B mult), b128 reads 2-way = free

__global__ __launch_bounds__(256, 2) void attn_mfma2(
    const bf16_t* __restrict__ qkv, const bf16_t* __restrict__ vt,
    float* __restrict__ out) {
  __shared__ bf16_t QsPs[TQ * AST];
  __shared__ bf16_t Ks[TK * AST];
  __shared__ bf16_t Vs[TK * AST];  // V^T tile: [d][key]

  const int tid  = threadIdx.x;
  const int lane = tid & 63;
  const int w    = tid >> 6;
  const int quad = lane >> 4;
  const int l15  = lane & 15;
  const int pi   = blockIdx.x;        // 0..15
  const int h    = blockIdx.y;
  const int z    = blockIdx.z;
  const int qb[2] = {pi, 31 - pi};
  const bf16_t* qkv_b = qkv + (size_t)z * S_LEN * 3072;
  const bf16_t* vt_bh = vt + ((size_t)z * NHEAD + h) * 64 * S_LEN;
  float* out_b = out + (size_t)z * S_LEN * DIM;

  // stage Q for both tiles (sequentially through QsPs), keep fragments
  bf16x8 aq[2][2];  // [tile][ks]
  for (int tile = 0; tile < 2; ++tile) {
    if (tile) __syncthreads();  // all frag reads of tile0 done before overwrite
    const int qg0 = qb[tile] * TQ;
#pragma unroll
    for (int p = 0; p < 2; ++p) {
      int id  = p * 256 + tid;
      int row = id >> 3;
      int c8  = (id & 7) * 8;
      bf16x8 v = *reinterpret_cast<const bf16x8*>(
          qkv_b + (size_t)(qg0 + row) * 3072 + h * 64 + c8);
      bf16x8 o;
#pragma unroll
      for (int e = 0; e < 8; ++e) o[e] = (bf16_t)((float)v[e] * 0.015625f);
      *reinterpret_cast<bf16x8*>(&QsPs[row * AST + c8]) = o;
    }
    __syncthreads();
#pragma unroll
    for (int ks = 0; ks < 2; ++ks)
      aq[tile][ks] = *reinterpret_cast<const bf16x8*>(
          &QsPs[(w * 16 + l15) * AST + ks * 32 + quad * 8]);
  }

  float m_run[2][4], l_run[2][4];
  floatx4 O[2][4];
#pragma unroll
  for (int t = 0; t < 2; ++t)
#pragma unroll
    for (int r = 0; r < 4; ++r) {
      m_run[t][r] = -1e30f; l_run[t][r] = 0.0f;
    }
#pragma unroll
  for (int t = 0; t < 2; ++t)
#pragma unroll
    for (int dt = 0; dt < 4; ++dt) O[t][dt] = (floatx4)(0.0f);

  const int ktEnd = qb[1] + 1;  // tile B bound (tile A skips via mask test)
  for (int kt = 0; kt < ktEnd; ++kt) {
    __syncthreads();  // prior-iter K/V readers done (kt=0: frag reads done)
#pragma unroll
    for (int p = 0; p < 2; ++p) {
      int id  = p * 256 + tid;
      int row = id >> 3;
      int c8  = (id & 7) * 8;
      *reinterpret_cast<bf16x8*>(&Ks[row * AST + c8]) =
          *reinterpret_cast<const bf16x8*>(
              qkv_b + (size_t)(kt * TK + row) * 3072 + 1024 + h * 64 + c8);
      *reinterpret_cast<bf16x8*>(&Vs[row * AST + c8]) =
          *reinterpret_cast<const bf16x8*>(
              vt_bh + (size_t)row * S_LEN + kt * TK + c8);
    }
    __syncthreads();

    // shared K and V^T fragments for this K-tile
    bf16x8 bk[4][2], bv[4][2];
#pragma unroll
    for (int i = 0; i < 4; ++i)
#pragma unroll
      for (int ks = 0; ks < 2; ++ks) {
        bk[i][ks] = *reinterpret_cast<const bf16x8*>(
            &Ks[(i * 16 + l15) * AST + ks * 32 + quad * 8]);
        bv[i][ks] = *reinterpret_cast<const bf16x8*>(
            &Vs[(i * 16 + l15) * AST + ks * 32 + quad * 8]);
      }

#pragma unroll
    for (int tile = 0; tile < 2; ++tile) {
      const int qtb = qb[tile] * TQ + w * 16;
      if (kt * TK > qtb + 15) continue;  // fully above diagonal: skip

      floatx4 s[4];
#pragma unroll
      for (int ktl = 0; ktl < 4; ++ktl) {
        s[ktl] = __builtin_amdgcn_mfma_f32_16x16x32_bf16(
            aq[tile][0], bk[ktl][0], (floatx4)(0.0f), 0, 0, 0);
        s[ktl] = __builtin_amdgcn_mfma_f32_16x16x32_bf16(
            aq[tile][1], bk[ktl][1], s[ktl], 0, 0, 0);
      }
      if (kt * TK + TK - 1 > qtb) {
#pragma unroll
        for (int ktl = 0; ktl < 4; ++ktl) {
          int gk = kt * TK + ktl * 16 + l15;
#pragma unroll
          for (int r = 0; r < 4; ++r) {
            int gq = qtb + quad * 4 + r;
            if (gk > gq) s[ktl][r] = -1e30f;
          }
        }
      }
      float lsum[4], alpha[4];
#pragma unroll
      for (int r = 0; r < 4; ++r) {
        float mv = fmaxf(fmaxf(s[0][r], s[1][r]), fmaxf(s[2][r], s[3][r]));
#pragma unroll
        for (int off = 1; off < 16; off <<= 1)
          mv = fmaxf(mv, __shfl_xor(mv, off));
        float mn = fmaxf(m_run[tile][r], mv);
        alpha[r] = __expf(m_run[tile][r] - mn);
        m_run[tile][r] = mn;
        lsum[r] = 0.0f;
      }
#pragma unroll
      for (int ktl = 0; ktl < 4; ++ktl)
#pragma unroll
        for (int r = 0; r < 4; ++r) {
          float p = __expf(s[ktl][r] - m_run[tile][r]);
          s[ktl][r] = p;
          lsum[r] += p;
        }
#pragma unroll
      for (int r = 0; r < 4; ++r) {
#pragma unroll
        for (int off = 1; off < 16; off <<= 1)
          lsum[r] += __shfl_xor(lsum[r], off);
        l_run[tile][r] = l_run[tile][r] * alpha[r] + lsum[r];
      }
#pragma unroll
      for (int dt = 0; dt < 4; ++dt)
#pragma unroll
        for (int r = 0; r < 4; ++r) O[tile][dt][r] *= alpha[r];
      // P -> LDS (wave-private rows of QsPs; in-order per-wave LDS)
#pragma unroll
      for (int ktl = 0; ktl < 4; ++ktl)
#pragma unroll
        for (int r = 0; r < 4; ++r)
          QsPs[(w * 16 + quad * 4 + r) * AST + ktl * 16 + l15] =
              (bf16_t)s[ktl][r];

      bf16x8 ap0 = *reinterpret_cast<const bf16x8*>(
          &QsPs[(w * 16 + l15) * AST + quad * 8]);
      bf16x8 ap1 = *reinterpret_cast<const bf16x8*>(
          &QsPs[(w * 16 + l15) * AST + 32 + quad * 8]);
#pragma unroll
      for (int dt = 0; dt < 4; ++dt) {
        O[tile][dt] = __builtin_amdgcn_mfma_f32_16x16x32_bf16(
            ap0, bv[dt][0], O[tile][dt], 0, 0, 0);
        O[tile][dt] = __builtin_amdgcn_mfma_f32_16x16x32_bf16(
            ap1, bv[dt][1], O[tile][dt], 0, 0, 0);
      }
    }
  }

  // epilogue: O / l -> out (f32), both tiles
#pragma unroll
  for (int tile = 0; tile < 2; ++tile) {
    const int qg0 = qb[tile] * TQ;
    float inv[4];
#pragma unroll
    for (int r = 0; r < 4; ++r) inv[r] = 1.0f / l_run[tile][r];
#pragma unroll
    for (int dt = 0; dt < 4; ++dt)
#pragma unroll
      for (int r = 0; r < 4; ++r)
        out_b[(size_t)(qg0 + w * 16 + quad * 4 + r) * DIM +
              h * 64 + dt * 16 + l15] = O[tile][dt][r] * inv[r];
  }
}

// ---------------------------------------------------------------------------
// out = LayerNorm(a + b) * g + beta (row = 1024, eps 1e-5). a generic dtype.
// Alias-safe in place (per-thread read-before-write).
// ---------------------------------------------------------------------------
template <typename TA>
__global__ __launch_bounds__(256) void add_ln_k(const TA* a,
                                                const float* b,
                                                const float* __restrict__ g,
                                                const float* __restrict__ be,
                                                float* out) {
  const int row = blockIdx.x;
  const int t   = threadIdx.x;
  const size_t base = (size_t)row * DIM;

  float x[4];
  {
    floatx4 bv = *reinterpret_cast<const floatx4*>(b + base + t * 4);
    if constexpr (sizeof(TA) == 2) {
      bf16x4 av = *reinterpret_cast<const bf16x4*>(a + base + t * 4);
#pragma unroll
      for (int i = 0; i < 4; ++i) x[i] = (float)av[i] + bv[i];
    } else {
      floatx4 av = *reinterpret_cast<const floatx4*>(a + base + t * 4);
#pragma unroll
      for (int i = 0; i < 4; ++i) x[i] = av[i] + bv[i];
    }
  }
  float s1 = 0.0f, s2 = 0.0f;
#pragma unroll
  for (int i = 0; i < 4; ++i) { s1 += x[i]; s2 += x[i] * x[i]; }
#pragma unroll
  for (int off = 32; off; off >>= 1) {
    s1 += __shfl_xor(s1, off);
    s2 += __shfl_xor(s2, off);
  }
  __shared__ float ls1[4], ls2[4];
  if ((t & 63) == 0) { ls1[t >> 6] = s1; ls2[t >> 6] = s2; }
  __syncthreads();
  float S1 = ls1[0] + ls1[1] + ls1[2] + ls1[3];
  float S2 = ls2[0] + ls2[1] + ls2[2] + ls2[3];
  float mu  = S1 * (1.0f / DIM);
  float var = S2 * (1.0f / DIM) - mu * mu;
  float rs  = rsqrtf(var + 1e-5f);
#pragma unroll
  for (int i = 0; i < 4; ++i) {
    int c = t * 4 + i;
    out[base + c] = (x[i] - mu) * rs * g[c] + be[c];
  }
}

// ---------------------------------------------------------------------------
extern "C" void kernel_launch(void* const* d_in, const int* in_sizes, int n_in,
                              void* d_out, int out_size, void* d_ws, size_t ws_size,
                              hipStream_t stream) {
  const float* x   = (const float*)d_in[0];
  const float* Wq  = (const float*)d_in[1];
  const float* Wk  = (const float*)d_in[2];
  const float* Wv  = (const float*)d_in[3];
  const float* bq  = (const float*)d_in[4];
  const float* bk  = (const float*)d_in[5];
  const float* bv  = (const float*)d_in[6];
  const float* g1  = (const float*)d_in[7];
  const float* be1 = (const float*)d_in[8];
  const float* W1  = (const float*)d_in[9];
  const float* b1  = (const float*)d_in[10];
  const float* W2  = (const float*)d_in[11];
  const float* b2  = (const float*)d_in[12];
  const float* g2  = (const float*)d_in[13];
  const float* be2 = (const float*)d_in[14];
  float* out = (float*)d_out;
  char*  ws  = (char*)d_ws;

  // ws layout (bytes), peak 38 MiB (proven safe):
  //   phase 1: WqkvT [0, 6291456)          3072 x 1024 bf16 (Wq|Wk|Wv ^T)
  //            qkv2  [6291456, 31457280)   4096 x 3072 bf16 (per batch-pair)
  //            vt    [31457280, 39845888)  32 x 64 x 2048 bf16
  //   phase 2: W1Tq  [0, 2097152)          1024 x 1024 bf16 (hidden quarter)
  //            W2Tq  [2097152, 4194304)    1024 x 1024 bf16
  //            mid   [4194304, 20971520)   8192 x 1024 bf16
  //            ffnO  [20971520, 37748736)  8192 x 1024 bf16 (accumulated)
  bf16_t* WqkvT = (bf16_t*)(ws);
  bf16_t* qkv2  = (bf16_t*)(ws + 6291456);
  bf16_t* vt    = (bf16_t*)(ws + 31457280);
  bf16_t* W1Tq  = (bf16_t*)(ws);
  bf16_t* W2Tq  = (bf16_t*)(ws + 2097152);
  bf16_t* mid   = (bf16_t*)(ws + 4194304);
  bf16_t* ffnO  = (bf16_t*)(ws + 20971520);

  dim3 tb(32, 8);
  // --- weight transposes (f32 -> bf16 NxK), one fused dispatch ---
  convT3<<<dim3(32, 32, 3), tb, 0, stream>>>(
      Wq, 1024, WqkvT, Wk, 1024, WqkvT + 1048576, Wv, 1024, WqkvT + 2097152, 1024);

  // --- QKV + attention, per batch-pair ---
  for (int p = 0; p < 2; ++p) {
    const float* xp   = x   + (size_t)p * 2 * S_LEN * DIM;
    float*       outp = out + (size_t)p * 2 * S_LEN * DIM;
    gemm_abt<float><<<dim3(8, 32, 3), 256, 0, stream>>>(
        xp, 1024, WqkvT, 1024, qkv2, 3072, 1024, bq, bk, bv, 1024, 0, 0);
    transpose_v<<<dim3(64, 2, 32), tb, 0, stream>>>(qkv2, vt);
    attn_mfma2<<<dim3(16, 16, 2), 256, 0, stream>>>(qkv2, vt, outp);
  }
  // h = LN(attn + x), in place in d_out
  add_ln_k<float><<<8192, 256, 0, stream>>>(out, x, g1, be1, out);

  // --- FFN in 4 hidden-quarters at full M=8192 ---
  for (int q = 0; q < 4; ++q) {
    convT3<<<dim3(32, 32, 2), tb, 0, stream>>>(
        W1 + q * 1024, 4096, W1Tq,
        W2 + (size_t)q * 1024 * 1024, 1024, W2Tq,
        nullptr, 0, nullptr, 1024);
    gemm_abt<float><<<dim3(8, 64, 1), 256, 0, stream>>>(
        out, 1024, W1Tq, 0, mid, 1024, 0, b1 + q * 1024, nullptr, nullptr,
        1024, 1, 0);
    gemm_abt<bf16_t><<<dim3(8, 64, 1), 256, 0, stream>>>(
        mid, 1024, W2Tq, 0, ffnO, 1024, 0, (q == 0) ? b2 : nullptr, nullptr,
        nullptr, 1024, 0, (q > 0) ? 1 : 0);
  }
  // out = LN(ffn + h), in place (h = d_out)
  add_ln_k<bf16_t><<<8192, 256, 0, stream>>>(ffnO, out, g2, be2, out);
}